// Round 4
// baseline (189.675 us; speedup 1.0000x reference)
//
#include <hip/hip_runtime.h>

// Problem constants (fixed by the reference): B=16 lists, N=1024, D=256.
#define BL 16
#define NL 1024
#define DD 256

typedef short bf16x8 __attribute__((ext_vector_type(8)));
typedef float f32x4 __attribute__((ext_vector_type(4)));

static __device__ __forceinline__ short f32_to_bf16(float f) {
  union { float f; unsigned u; } v; v.f = f;
  unsigned r = (v.u + 0x7FFFu + ((v.u >> 16) & 1u)) >> 16;  // RNE
  return (short)r;
}

// Async 16B global -> LDS. LDS dest must be wave-uniform base + lane*16
// (m104/m108). Global source address IS per-lane -> pre-swizzled source.
static __device__ __forceinline__ void g2l16(const short* g, short* l) {
  __builtin_amdgcn_global_load_lds(
      (const __attribute__((address_space(1))) void*)g,
      (__attribute__((address_space(3))) void*)l, 16, 0, 0);
}

// ---- Kernel 1: prep. Blocks [0,4096): X fp32->bf16. [4096,4608): W transpose.
__global__ __launch_bounds__(256) void k_prep(const float* __restrict__ X,
                                              const float* __restrict__ Wu,
                                              const float* __restrict__ Wl,
                                              short* __restrict__ Xb,
                                              short* __restrict__ WTu,
                                              short* __restrict__ WTl) {
  const int bid = blockIdx.x;
  if (bid < 4096) {
    int i = bid * 256 + threadIdx.x;  // float4 groups over 16384*256 floats
    const float4 v = ((const float4*)X)[i];
    short4 o;
    o.x = f32_to_bf16(v.x); o.y = f32_to_bf16(v.y);
    o.z = f32_to_bf16(v.z); o.w = f32_to_bf16(v.w);
    ((short4*)Xb)[i] = o;
  } else {
    const int id = bid - 4096;           // [0,512)
    const int z = id >> 8, d = id & 255; // matrix, source row of W
    const float* W = z ? Wl : Wu;
    short* WT = z ? WTl : WTu;
    const int e = threadIdx.x;
    WT[e * DD + d] = f32_to_bf16(W[d * DD + e]);  // WT[e][d] = W[d][e]
  }
}

// Off-diagonal 16x64 tile: C = Y(16xK, LDS) x B(64xK, global L2)^T, K=256.
// SWAPPED mfma(bf, af): D rows <- q (B rows), D cols <- p (Y rows). Each lane
// holds 4 consecutive q at fixed p -> plain f32x4 stores; L2 write-back
// merges the two 64B halves of each 128B line (NT stores did NOT merge:
// round-3 WRITE_SIZE was 2.2x output size).
static __device__ __forceinline__ void tile_off(const short* __restrict__ Ylds,
                                                const short* __restrict__ Bg,
                                                float* __restrict__ Ob,
                                                int p0, int q0, float bias,
                                                int r, int quad) {
  f32x4 acc[4] = {};
#pragma unroll
  for (int ks = 0; ks < 8; ++ks) {
    const int abyte = (r * 512 + ks * 64 + quad * 16) ^ ((r & 7) << 4);
    const bf16x8 af = *(const bf16x8*)((const char*)Ylds + abyte);
    bf16x8 bf[4];
#pragma unroll
    for (int nt = 0; nt < 4; ++nt)
      bf[nt] = *(const bf16x8*)(Bg + (size_t)(nt * 16 + r) * DD + ks * 32 + quad * 8);
#pragma unroll
    for (int nt = 0; nt < 4; ++nt)
      acc[nt] = __builtin_amdgcn_mfma_f32_16x16x32_bf16(bf[nt], af, acc[nt], 0, 0, 0);
  }
  float* row = Ob + (size_t)(p0 + r) * NL;
#pragma unroll
  for (int nt = 0; nt < 4; ++nt) {
    f32x4 v;
    v[0] = acc[nt][0] + bias; v[1] = acc[nt][1] + bias;
    v[2] = acc[nt][2] + bias; v[3] = acc[nt][3] + bias;
    *(f32x4*)(row + q0 + nt * 16 + quad * 4) = v;
  }
}

// Diagonal tile: dual accumulators (U and L), per-element select, f32x4 store.
static __device__ __forceinline__ void tile_diag(const short* __restrict__ Yu,
                                                 const short* __restrict__ Yl,
                                                 const short* __restrict__ Bg,
                                                 float* __restrict__ Ob,
                                                 int p0, int q0, float ub, float lb,
                                                 int r, int quad) {
  f32x4 aU[4] = {}, aL[4] = {};
#pragma unroll
  for (int ks = 0; ks < 8; ++ks) {
    const int abyte = (r * 512 + ks * 64 + quad * 16) ^ ((r & 7) << 4);
    const bf16x8 afu = *(const bf16x8*)((const char*)Yu + abyte);
    const bf16x8 afl = *(const bf16x8*)((const char*)Yl + abyte);
    bf16x8 bf[4];
#pragma unroll
    for (int nt = 0; nt < 4; ++nt)
      bf[nt] = *(const bf16x8*)(Bg + (size_t)(nt * 16 + r) * DD + ks * 32 + quad * 8);
#pragma unroll
    for (int nt = 0; nt < 4; ++nt) {
      aU[nt] = __builtin_amdgcn_mfma_f32_16x16x32_bf16(bf[nt], afu, aU[nt], 0, 0, 0);
      aL[nt] = __builtin_amdgcn_mfma_f32_16x16x32_bf16(bf[nt], afl, aL[nt], 0, 0, 0);
    }
  }
  const int p = p0 + r;
  float* row = Ob + (size_t)p * NL;
#pragma unroll
  for (int nt = 0; nt < 4; ++nt) {
    f32x4 v;
#pragma unroll
    for (int i = 0; i < 4; ++i) {
      const int q = q0 + nt * 16 + quad * 4 + i;
      v[i] = (q >= p) ? (aU[nt][i] + ub) : (aL[nt][i] + lb);
    }
    *(f32x4*)(row + q0 + nt * 16 + quad * 4) = v;
  }
}

// ---- Kernel 2: fused stage1+stage2. One block per (list b, 16-row p-strip).
// Grid = 1024 blocks (64 strips x 16 lists) = 4 blocks/CU exact; 512 threads.
// LDS 24KB; __launch_bounds__(512,8) caps VGPR at 64 -> 32 waves/CU (100%).
// bid = pt*16 + b -> XCD = bid%8 = b%8: 2 lists (1MB X) pinned per XCD L2.
// Phase 1: Y_U/Y_L[16x256] = Xp*W (wave w -> cols [w*32,+32), both matrices).
// Phase 2 (barrier-free): wave w -> q-tiles w and w+8 of the 16x1024 strip.
__global__ __launch_bounds__(512, 8) void k_fused(const short* __restrict__ Xb,
                                                  const short* __restrict__ WTu,
                                                  const short* __restrict__ WTl,
                                                  const float* __restrict__ bu_p,
                                                  const float* __restrict__ bl_p,
                                                  float* __restrict__ out) {
  __shared__ short Asw[16 * 256];  // swizzled Xp strip, 8 KB
  __shared__ short Yu[16 * 256];   // swizzled Y_upper,  8 KB
  __shared__ short Yl[16 * 256];   // swizzled Y_lower,  8 KB

  const int bid = blockIdx.x;
  const int b = bid & 15, pt = bid >> 4;  // pt in [0,64): 16-row strip
  const int t = threadIdx.x, lane = t & 63, w = t >> 6;
  const int r = lane & 15, quad = lane >> 4;
  const size_t listoff = (size_t)b * NL * DD;
  const short* Ap = Xb + listoff + (size_t)pt * 16 * DD;  // 16 x 256 bf16

  // ---- stage Xp into LDS, XOR-swizzled via pre-swizzled global source ----
  // 512 16B-chunks; reads at (row*512+kb)^((row&7)<<4) -> src chunk c^((c>>5)&7).
  {
    const int c = t;  // per wave: uniform base + lane*16
    const int src = c ^ ((c >> 5) & 7);
    g2l16(Ap + src * 8, Asw + c * 8);
  }
  __syncthreads();  // compiler drains vmcnt before s_barrier

  // ---- phase 1: Y = Xp * W for both matrices; wave w -> cols [w*32,+32) ----
  {
    const int n0 = w * 32;
    f32x4 aU[2] = {}, aL[2] = {};
#pragma unroll
    for (int ks = 0; ks < 8; ++ks) {
      const int abyte = (r * 512 + ks * 64 + quad * 16) ^ ((r & 7) << 4);
      const bf16x8 af = *(const bf16x8*)((const char*)Asw + abyte);
      bf16x8 bfu[2], bfl[2];
#pragma unroll
      for (int nt = 0; nt < 2; ++nt) {
        const int off = (n0 + nt * 16 + r) * DD + ks * 32 + quad * 8;
        bfu[nt] = *(const bf16x8*)(WTu + off);
        bfl[nt] = *(const bf16x8*)(WTl + off);
      }
#pragma unroll
      for (int nt = 0; nt < 2; ++nt) {
        aU[nt] = __builtin_amdgcn_mfma_f32_16x16x32_bf16(af, bfu[nt], aU[nt], 0, 0, 0);
        aL[nt] = __builtin_amdgcn_mfma_f32_16x16x32_bf16(af, bfl[nt], aL[nt], 0, 0, 0);
      }
    }
    // write Y (bf16) into swizzled LDS: D[m][n] -> row m = quad*4+i, col n0+nt*16+r
#pragma unroll
    for (int nt = 0; nt < 2; ++nt)
#pragma unroll
      for (int i = 0; i < 4; ++i) {
        const int row = quad * 4 + i;
        const int col = n0 + nt * 16 + r;
        const int byte = (row * 512 + col * 2) ^ ((row & 7) << 4);
        *(short*)((char*)Yu + byte) = f32_to_bf16(aU[nt][i]);
        *(short*)((char*)Yl + byte) = f32_to_bf16(aL[nt][i]);
      }
  }
  __syncthreads();

  // ---- phase 2: barrier-free; wave w owns q-tiles w and w+8 ----
  const float ub = bu_p[0], lb = bl_p[0];
  float* Ob = out + (size_t)b * NL * NL;
  const short* Bl = Xb + listoff;
  const int p0 = pt * 16;
  const int dq = pt >> 2;  // the 64-wide q-tile containing the diagonal

  for (int qq = 0; qq < 2; ++qq) {
    const int qt = w + qq * 8;
    const short* Bg = Bl + (size_t)qt * 64 * DD;
    const int q0 = qt * 64;
    if (qt > dq) {
      tile_off(Yu, Bg, Ob, p0, q0, ub, r, quad);
    } else if (qt < dq) {
      tile_off(Yl, Bg, Ob, p0, q0, lb, r, quad);
    } else {
      tile_diag(Yu, Yl, Bg, Ob, p0, q0, ub, lb, r, quad);
    }
  }
}

extern "C" void kernel_launch(void* const* d_in, const int* in_sizes, int n_in,
                              void* d_out, int out_size, void* d_ws, size_t ws_size,
                              hipStream_t stream) {
  const float* feats = (const float*)d_in[0];   // [B*N, D] fp32
  const float* Wu    = (const float*)d_in[1];   // [1, D, D]
  const float* bu    = (const float*)d_in[2];   // [1]
  const float* Wl    = (const float*)d_in[3];   // [1, D, D]
  const float* bl    = (const float*)d_in[4];   // [1]
  float* out = (float*)d_out;                   // [B, N, N] fp32

  char* ws = (char*)d_ws;
  short* Xb  = (short*)(ws);                                   // 8 MB bf16 X
  short* WTu = (short*)(ws + (size_t)8 * 1024 * 1024);         // 128 KB
  short* WTl = (short*)(ws + (size_t)8 * 1024 * 1024 + DD * DD * 2);

  // Prep: X->bf16 (4096 blocks) + W transpose (512 blocks), one dispatch.
  k_prep<<<4096 + 512, 256, 0, stream>>>(feats, Wu, Wl, Xb, WTu, WTl);

  // Fused stage1+stage2: 1024 blocks (64 p-strips x 16 lists), 512 threads.
  // bid = pt*16 + b  ->  XCD = bid%8 = b%8: each list L2-pinned to one XCD.
  k_fused<<<1024, 512, 0, stream>>>(Xb, WTu, WTl, bu, bl, out);
}

// Round 5
// 181.903 us; speedup vs baseline: 1.0427x; 1.0427x over previous
//
#include <hip/hip_runtime.h>

// Problem constants (fixed by the reference): B=16 lists, N=1024, D=256.
#define BL 16
#define NL 1024
#define DD 256

typedef short bf16x8 __attribute__((ext_vector_type(8)));
typedef float f32x4 __attribute__((ext_vector_type(4)));

static __device__ __forceinline__ short f32_to_bf16(float f) {
  union { float f; unsigned u; } v; v.f = f;
  unsigned r = (v.u + 0x7FFFu + ((v.u >> 16) & 1u)) >> 16;  // RNE
  return (short)r;
}

// Async 16B global -> LDS. LDS dest must be wave-uniform base + lane*16
// (m104/m108). Global source address IS per-lane -> pre-swizzled source.
static __device__ __forceinline__ void g2l16(const short* g, short* l) {
  __builtin_amdgcn_global_load_lds(
      (const __attribute__((address_space(1))) void*)g,
      (__attribute__((address_space(3))) void*)l, 16, 0, 0);
}

// ---- Kernel 1: prep. Blocks [0,4096): X fp32->bf16. [4096,4608): W transpose.
__global__ __launch_bounds__(256) void k_prep(const float* __restrict__ X,
                                              const float* __restrict__ Wu,
                                              const float* __restrict__ Wl,
                                              short* __restrict__ Xb,
                                              short* __restrict__ WTu,
                                              short* __restrict__ WTl) {
  const int bid = blockIdx.x;
  if (bid < 4096) {
    int i = bid * 256 + threadIdx.x;  // float4 groups over 16384*256 floats
    const float4 v = ((const float4*)X)[i];
    short4 o;
    o.x = f32_to_bf16(v.x); o.y = f32_to_bf16(v.y);
    o.z = f32_to_bf16(v.z); o.w = f32_to_bf16(v.w);
    ((short4*)Xb)[i] = o;
  } else {
    const int id = bid - 4096;           // [0,512)
    const int z = id >> 8, d = id & 255; // matrix, source row of W
    const float* W = z ? Wl : Wu;
    short* WT = z ? WTl : WTu;
    const int e = threadIdx.x;
    WT[e * DD + d] = f32_to_bf16(W[d * DD + e]);  // WT[e][d] = W[d][e]
  }
}

// ---- Kernel 2: fused stage1+stage2. One block per (list b, 16-row p-strip).
// Grid = 1024 blocks (64 strips x 16 lists), 512 threads = 8 waves.
// __launch_bounds__(512,2): VGPR free up to 256 -> compiler keeps ~8 loads in
// flight (R4's (512,8)->VGPR32 serialized every load: 110us).
// bid = pt*16 + b -> XCD = bid%8 = b%8: 2 lists (1MB X) pinned per XCD L2.
// Phase 1: Y_U/Y_L[16x256] = Xp*W (wave w -> cols [w*32,+32), both matrices).
// Phase 2 (barrier-free): wave w computes q-tiles w AND w+8 in one ks loop
// (shared A fragment, 8 independent global B loads + 8 MFMA per step).
// Diagonal tile: pair pass stores Upper everywhere; owning wave then
// recomputes with Y_L and overwrites q<p (same-thread order => correct).
__global__ __launch_bounds__(512, 2) void k_fused(const short* __restrict__ Xb,
                                                  const short* __restrict__ WTu,
                                                  const short* __restrict__ WTl,
                                                  const float* __restrict__ bu_p,
                                                  const float* __restrict__ bl_p,
                                                  float* __restrict__ out) {
  __shared__ short Asw[16 * 256];  // swizzled Xp strip, 8 KB
  __shared__ short Yu[16 * 256];   // swizzled Y_upper,  8 KB
  __shared__ short Yl[16 * 256];   // swizzled Y_lower,  8 KB

  const int bid = blockIdx.x;
  const int b = bid & 15, pt = bid >> 4;  // pt in [0,64): 16-row strip
  const int t = threadIdx.x, lane = t & 63, w = t >> 6;
  const int r = lane & 15, quad = lane >> 4;
  const size_t listoff = (size_t)b * NL * DD;
  const short* Ap = Xb + listoff + (size_t)pt * 16 * DD;  // 16 x 256 bf16

  // ---- stage Xp into LDS, XOR-swizzled via pre-swizzled global source ----
  // 512 16B-chunks; reads at (row*512+kb)^((row&7)<<4) -> src chunk c^((c>>5)&7).
  {
    const int c = t;  // per wave: uniform base + lane*16
    const int src = c ^ ((c >> 5) & 7);
    g2l16(Ap + src * 8, Asw + c * 8);
  }
  __syncthreads();  // compiler drains vmcnt before s_barrier

  // ---- phase 1: Y = Xp * W for both matrices; wave w -> cols [w*32,+32) ----
  {
    const int n0 = w * 32;
    f32x4 aU[2] = {}, aL[2] = {};
#pragma unroll
    for (int ks = 0; ks < 8; ++ks) {
      const int abyte = (r * 512 + ks * 64 + quad * 16) ^ ((r & 7) << 4);
      const bf16x8 af = *(const bf16x8*)((const char*)Asw + abyte);
      bf16x8 bfu[2], bfl[2];
#pragma unroll
      for (int nt = 0; nt < 2; ++nt) {
        const int off = (n0 + nt * 16 + r) * DD + ks * 32 + quad * 8;
        bfu[nt] = *(const bf16x8*)(WTu + off);
        bfl[nt] = *(const bf16x8*)(WTl + off);
      }
#pragma unroll
      for (int nt = 0; nt < 2; ++nt) {
        aU[nt] = __builtin_amdgcn_mfma_f32_16x16x32_bf16(af, bfu[nt], aU[nt], 0, 0, 0);
        aL[nt] = __builtin_amdgcn_mfma_f32_16x16x32_bf16(af, bfl[nt], aL[nt], 0, 0, 0);
      }
    }
    // write Y (bf16) into swizzled LDS: D[m][n] -> row m = quad*4+i, col n0+nt*16+r
#pragma unroll
    for (int nt = 0; nt < 2; ++nt)
#pragma unroll
      for (int i = 0; i < 4; ++i) {
        const int row = quad * 4 + i;
        const int col = n0 + nt * 16 + r;
        const int byte = (row * 512 + col * 2) ^ ((row & 7) << 4);
        *(short*)((char*)Yu + byte) = f32_to_bf16(aU[nt][i]);
        *(short*)((char*)Yl + byte) = f32_to_bf16(aL[nt][i]);
      }
  }
  __syncthreads();

  // ---- phase 2: barrier-free; wave w owns q-tiles w and w+8, one ks loop ----
  const float ub = bu_p[0], lb = bl_p[0];
  float* Ob = out + (size_t)b * NL * NL;
  const short* Bl = Xb + listoff;
  const int p0 = pt * 16;
  const int dq = pt >> 2;  // the 64-wide q-tile containing the diagonal

  const int qtA = w, qtB = w + 8;
  const short* YA = (qtA >= dq) ? Yu : Yl;  // diag tile -> Upper in pair pass
  const short* YB = (qtB >= dq) ? Yu : Yl;
  const float bA = (qtA >= dq) ? ub : lb;
  const float bB = (qtB >= dq) ? ub : lb;
  const short* BgA = Bl + (size_t)qtA * 64 * DD;
  const short* BgB = Bl + (size_t)qtB * 64 * DD;

  f32x4 accA[4] = {}, accB[4] = {};
#pragma unroll
  for (int ks = 0; ks < 8; ++ks) {
    const int abyte = (r * 512 + ks * 64 + quad * 16) ^ ((r & 7) << 4);
    const bf16x8 afA = *(const bf16x8*)((const char*)YA + abyte);
    const bf16x8 afB = *(const bf16x8*)((const char*)YB + abyte);
    bf16x8 bfA[4], bfB[4];
#pragma unroll
    for (int nt = 0; nt < 4; ++nt)
      bfA[nt] = *(const bf16x8*)(BgA + (size_t)(nt * 16 + r) * DD + ks * 32 + quad * 8);
#pragma unroll
    for (int nt = 0; nt < 4; ++nt)
      bfB[nt] = *(const bf16x8*)(BgB + (size_t)(nt * 16 + r) * DD + ks * 32 + quad * 8);
#pragma unroll
    for (int nt = 0; nt < 4; ++nt) {
      accA[nt] = __builtin_amdgcn_mfma_f32_16x16x32_bf16(bfA[nt], afA, accA[nt], 0, 0, 0);
      accB[nt] = __builtin_amdgcn_mfma_f32_16x16x32_bf16(bfB[nt], afB, accB[nt], 0, 0, 0);
    }
  }
  // stores: lane holds rows p0+r, 4 consecutive q per f32x4 (L2 merges lines)
  float* row = Ob + (size_t)(p0 + r) * NL;
#pragma unroll
  for (int nt = 0; nt < 4; ++nt) {
    f32x4 vA, vB;
#pragma unroll
    for (int i = 0; i < 4; ++i) { vA[i] = accA[nt][i] + bA; vB[i] = accB[nt][i] + bB; }
    *(f32x4*)(row + qtA * 64 + nt * 16 + quad * 4) = vA;
    *(f32x4*)(row + qtB * 64 + nt * 16 + quad * 4) = vB;
  }

  // ---- diag fixup: owning wave recomputes lower part with Y_L ----
  if (qtA == dq || qtB == dq) {
    const short* Bg = (qtA == dq) ? BgA : BgB;
    const int q0 = dq * 64;
    f32x4 accL[4] = {};
#pragma unroll
    for (int ks = 0; ks < 8; ++ks) {
      const int abyte = (r * 512 + ks * 64 + quad * 16) ^ ((r & 7) << 4);
      const bf16x8 afl = *(const bf16x8*)((const char*)Yl + abyte);
      bf16x8 bf[4];
#pragma unroll
      for (int nt = 0; nt < 4; ++nt)
        bf[nt] = *(const bf16x8*)(Bg + (size_t)(nt * 16 + r) * DD + ks * 32 + quad * 8);
#pragma unroll
      for (int nt = 0; nt < 4; ++nt)
        accL[nt] = __builtin_amdgcn_mfma_f32_16x16x32_bf16(bf[nt], afl, accL[nt], 0, 0, 0);
    }
    const int p = p0 + r;
#pragma unroll
    for (int nt = 0; nt < 4; ++nt)
#pragma unroll
      for (int i = 0; i < 4; ++i) {
        const int q = q0 + nt * 16 + quad * 4 + i;
        if (q < p) row[q] = accL[nt][i] + lb;
      }
  }
}

extern "C" void kernel_launch(void* const* d_in, const int* in_sizes, int n_in,
                              void* d_out, int out_size, void* d_ws, size_t ws_size,
                              hipStream_t stream) {
  const float* feats = (const float*)d_in[0];   // [B*N, D] fp32
  const float* Wu    = (const float*)d_in[1];   // [1, D, D]
  const float* bu    = (const float*)d_in[2];   // [1]
  const float* Wl    = (const float*)d_in[3];   // [1, D, D]
  const float* bl    = (const float*)d_in[4];   // [1]
  float* out = (float*)d_out;                   // [B, N, N] fp32

  char* ws = (char*)d_ws;
  short* Xb  = (short*)(ws);                                   // 8 MB bf16 X
  short* WTu = (short*)(ws + (size_t)8 * 1024 * 1024);         // 128 KB
  short* WTl = (short*)(ws + (size_t)8 * 1024 * 1024 + DD * DD * 2);

  // Prep: X->bf16 (4096 blocks) + W transpose (512 blocks), one dispatch.
  k_prep<<<4096 + 512, 256, 0, stream>>>(feats, Wu, Wl, Xb, WTu, WTl);

  // Fused stage1+stage2: 1024 blocks (64 p-strips x 16 lists), 512 threads.
  // bid = pt*16 + b  ->  XCD = bid%8 = b%8: each list L2-pinned to one XCD.
  k_fused<<<1024, 512, 0, stream>>>(Xb, WTu, WTl, bu, bl, out);
}

// Round 6
// 130.485 us; speedup vs baseline: 1.4536x; 1.3940x over previous
//
#include <hip/hip_runtime.h>

// Problem constants (fixed by the reference): B=16 lists, N=1024, D=256.
#define BL 16
#define NL 1024
#define DD 256

typedef short bf16x8 __attribute__((ext_vector_type(8)));
typedef float f32x4 __attribute__((ext_vector_type(4)));

static __device__ __forceinline__ short f32_to_bf16(float f) {
  union { float f; unsigned u; } v; v.f = f;
  unsigned r = (v.u + 0x7FFFu + ((v.u >> 16) & 1u)) >> 16;  // RNE
  return (short)r;
}

// Async 16B global -> LDS. LDS dest must be wave-uniform base + lane*16
// (m104/m108). Global source address IS per-lane -> pre-swizzled source.
static __device__ __forceinline__ void g2l16(const short* g, short* l) {
  __builtin_amdgcn_global_load_lds(
      (const __attribute__((address_space(1))) void*)g,
      (__attribute__((address_space(3))) void*)l, 16, 0, 0);
}

// ---- Kernel 1: prep. Blocks [0,4096): X fp32->bf16. [4096,4608): W transpose.
__global__ __launch_bounds__(256) void k_prep(const float* __restrict__ X,
                                              const float* __restrict__ Wu,
                                              const float* __restrict__ Wl,
                                              short* __restrict__ Xb,
                                              short* __restrict__ WTu,
                                              short* __restrict__ WTl) {
  const int bid = blockIdx.x;
  if (bid < 4096) {
    int i = bid * 256 + threadIdx.x;  // float4 groups over 16384*256 floats
    const float4 v = ((const float4*)X)[i];
    short4 o;
    o.x = f32_to_bf16(v.x); o.y = f32_to_bf16(v.y);
    o.z = f32_to_bf16(v.z); o.w = f32_to_bf16(v.w);
    ((short4*)Xb)[i] = o;
  } else {
    const int id = bid - 4096;           // [0,512)
    const int z = id >> 8, d = id & 255; // matrix, source row of W
    const float* W = z ? Wl : Wu;
    short* WT = z ? WTl : WTu;
    const int e = threadIdx.x;
    WT[e * DD + d] = f32_to_bf16(W[d * DD + e]);  // WT[e][d] = W[d][e]
  }
}

// ---- Kernel 2: fused stage1+stage2. One block per (list b, 64-row p-strip).
// Grid = 256 blocks (16 strips x 16 lists) = exactly 1/CU; 1024 thr = 16 waves
// (4 waves/SIMD). B-panel read ONCE per block -> total B traffic 128 MB (was
// 512 MB in R5 with 1024 small blocks: time tracked that traffic, 72->103us).
// bid = pt*16 + b -> XCD = bid%8 = b%8: 2 lists pinned per XCD L2.
// Phase 1: Y_U/Y_L[64x256] = Xp*W; wave w -> cols [w*16,+16), both matrices.
// Phase 2 (barrier-free): wave w owns q-tile w (64x64 out, 16 MFMA : 4 loads).
// Diag tile (qt==pt): pair pass stores Upper; owning wave recomputes with Y_L
// and overwrites q<p (same lane writes same addresses => ordered).
__global__ __launch_bounds__(1024, 4) void k_fused(const short* __restrict__ Xb,
                                                   const short* __restrict__ WTu,
                                                   const short* __restrict__ WTl,
                                                   const float* __restrict__ bu_p,
                                                   const float* __restrict__ bl_p,
                                                   float* __restrict__ out) {
  __shared__ short Asw[64 * 256];  // swizzled Xp strip, 32 KB
  __shared__ short Yu[64 * 256];   // swizzled Y_upper,  32 KB
  __shared__ short Yl[64 * 256];   // swizzled Y_lower,  32 KB

  const int bid = blockIdx.x;
  const int b = bid & 15, pt = bid >> 4;  // pt in [0,16): 64-row strip
  const int t = threadIdx.x, lane = t & 63, w = t >> 6;  // w in [0,16)
  const int r = lane & 15, quad = lane >> 4;
  const size_t listoff = (size_t)b * NL * DD;
  const short* Ap = Xb + listoff + (size_t)pt * 64 * DD;  // 64 x 256 bf16

  // ---- stage Xp into LDS, XOR-swizzled via pre-swizzled global source ----
  // 2048 16B-chunks (32/row); reads at (row*512+kb)^((row&7)<<4)
  //  -> src chunk c ^ ((c>>5)&7).
#pragma unroll
  for (int i = 0; i < 2; ++i) {
    const int c = i * 1024 + t;  // per wave: uniform base + lane*16
    const int src = c ^ ((c >> 5) & 7);
    g2l16(Ap + src * 8, Asw + c * 8);
  }
  __syncthreads();  // compiler drains vmcnt before s_barrier

  // ---- phase 1: Y = Xp * W for both matrices; wave w -> cols [w*16,+16) ----
  {
    const int n0 = w * 16;
    f32x4 aU[4] = {}, aL[4] = {};
#pragma unroll
    for (int ks = 0; ks < 8; ++ks) {
      bf16x8 af[4];
#pragma unroll
      for (int mt = 0; mt < 4; ++mt) {
        const int row = mt * 16 + r;
        const int abyte = (row * 512 + ks * 64 + quad * 16) ^ ((row & 7) << 4);
        af[mt] = *(const bf16x8*)((const char*)Asw + abyte);
      }
      const int off = (n0 + r) * DD + ks * 32 + quad * 8;
      const bf16x8 bfu = *(const bf16x8*)(WTu + off);
      const bf16x8 bfl = *(const bf16x8*)(WTl + off);
#pragma unroll
      for (int mt = 0; mt < 4; ++mt) {
        aU[mt] = __builtin_amdgcn_mfma_f32_16x16x32_bf16(af[mt], bfu, aU[mt], 0, 0, 0);
        aL[mt] = __builtin_amdgcn_mfma_f32_16x16x32_bf16(af[mt], bfl, aL[mt], 0, 0, 0);
      }
    }
    // write Y (bf16) into swizzled LDS: D[m][n]: row = mt*16+quad*4+i, col = n0+r
#pragma unroll
    for (int mt = 0; mt < 4; ++mt)
#pragma unroll
      for (int i = 0; i < 4; ++i) {
        const int row = mt * 16 + quad * 4 + i;
        const int col = n0 + r;
        const int byte = (row * 512 + col * 2) ^ ((row & 7) << 4);
        *(short*)((char*)Yu + byte) = f32_to_bf16(aU[mt][i]);
        *(short*)((char*)Yl + byte) = f32_to_bf16(aL[mt][i]);
      }
  }
  __syncthreads();

  // ---- phase 2: barrier-free; wave w owns q-tile w (64 cols) ----
  const float ub = bu_p[0], lb = bl_p[0];
  float* Ob = out + (size_t)b * NL * NL;
  const int p0 = pt * 64;
  const int qt = w, q0 = qt * 64;
  const short* Bg = Xb + listoff + (size_t)qt * 64 * DD;
  const short* YA = (qt >= pt) ? Yu : Yl;  // diag tile -> Upper in pair pass
  const float bias = (qt >= pt) ? ub : lb;

  f32x4 acc[4][4] = {};  // [nt][mt]: D rows <- q (B rows), cols <- p (Y rows)
#pragma unroll
  for (int ks = 0; ks < 8; ++ks) {
    bf16x8 af[4], bf[4];
#pragma unroll
    for (int mt = 0; mt < 4; ++mt) {
      const int row = mt * 16 + r;
      const int abyte = (row * 512 + ks * 64 + quad * 16) ^ ((row & 7) << 4);
      af[mt] = *(const bf16x8*)((const char*)YA + abyte);
    }
#pragma unroll
    for (int nt = 0; nt < 4; ++nt)
      bf[nt] = *(const bf16x8*)(Bg + (size_t)(nt * 16 + r) * DD + ks * 32 + quad * 8);
#pragma unroll
    for (int nt = 0; nt < 4; ++nt)
#pragma unroll
      for (int mt = 0; mt < 4; ++mt)
        acc[nt][mt] = __builtin_amdgcn_mfma_f32_16x16x32_bf16(bf[nt], af[mt],
                                                              acc[nt][mt], 0, 0, 0);
  }
  // stores: lane holds row p0+mt*16+r, 4 consecutive q per f32x4 (L2 merges)
#pragma unroll
  for (int mt = 0; mt < 4; ++mt) {
    float* row = Ob + (size_t)(p0 + mt * 16 + r) * NL;
#pragma unroll
    for (int nt = 0; nt < 4; ++nt) {
      f32x4 v;
#pragma unroll
      for (int i = 0; i < 4; ++i) v[i] = acc[nt][mt][i] + bias;
      *(f32x4*)(row + q0 + nt * 16 + quad * 4) = v;
    }
  }

  // ---- diag fixup: wave pt recomputes lower part with Y_L, overwrites q<p ----
  if (qt == pt) {
    f32x4 accL[4][4] = {};
#pragma unroll
    for (int ks = 0; ks < 8; ++ks) {
      bf16x8 af[4], bf[4];
#pragma unroll
      for (int mt = 0; mt < 4; ++mt) {
        const int row = mt * 16 + r;
        const int abyte = (row * 512 + ks * 64 + quad * 16) ^ ((row & 7) << 4);
        af[mt] = *(const bf16x8*)((const char*)Yl + abyte);
      }
#pragma unroll
      for (int nt = 0; nt < 4; ++nt)
        bf[nt] = *(const bf16x8*)(Bg + (size_t)(nt * 16 + r) * DD + ks * 32 + quad * 8);
#pragma unroll
      for (int nt = 0; nt < 4; ++nt)
#pragma unroll
        for (int mt = 0; mt < 4; ++mt)
          accL[nt][mt] = __builtin_amdgcn_mfma_f32_16x16x32_bf16(bf[nt], af[mt],
                                                                 accL[nt][mt], 0, 0, 0);
    }
#pragma unroll
    for (int mt = 0; mt < 4; ++mt) {
      const int p = p0 + mt * 16 + r;
      float* row = Ob + (size_t)p * NL;
#pragma unroll
      for (int nt = 0; nt < 4; ++nt)
#pragma unroll
        for (int i = 0; i < 4; ++i) {
          const int q = q0 + nt * 16 + quad * 4 + i;
          if (q < p) row[q] = accL[nt][mt][i] + lb;
        }
    }
  }
}

extern "C" void kernel_launch(void* const* d_in, const int* in_sizes, int n_in,
                              void* d_out, int out_size, void* d_ws, size_t ws_size,
                              hipStream_t stream) {
  const float* feats = (const float*)d_in[0];   // [B*N, D] fp32
  const float* Wu    = (const float*)d_in[1];   // [1, D, D]
  const float* bu    = (const float*)d_in[2];   // [1]
  const float* Wl    = (const float*)d_in[3];   // [1, D, D]
  const float* bl    = (const float*)d_in[4];   // [1]
  float* out = (float*)d_out;                   // [B, N, N] fp32

  char* ws = (char*)d_ws;
  short* Xb  = (short*)(ws);                                   // 8 MB bf16 X
  short* WTu = (short*)(ws + (size_t)8 * 1024 * 1024);         // 128 KB
  short* WTl = (short*)(ws + (size_t)8 * 1024 * 1024 + DD * DD * 2);

  // Prep: X->bf16 (4096 blocks) + W transpose (512 blocks), one dispatch.
  k_prep<<<4096 + 512, 256, 0, stream>>>(feats, Wu, Wl, Xb, WTu, WTl);

  // Fused stage1+stage2: 256 blocks (16 p-strips x 16 lists), 1024 threads.
  // bid = pt*16 + b  ->  XCD = bid%8 = b%8: each list L2-pinned to one XCD.
  k_fused<<<256, 1024, 0, stream>>>(Xb, WTu, WTl, bu, bl, out);
}

// Round 7
// 130.126 us; speedup vs baseline: 1.4576x; 1.0028x over previous
//
#include <hip/hip_runtime.h>

// Problem constants (fixed by the reference): B=16 lists, N=1024, D=256.
#define BL 16
#define NL 1024
#define DD 256

typedef short bf16x8 __attribute__((ext_vector_type(8)));
typedef float f32x4 __attribute__((ext_vector_type(4)));

static __device__ __forceinline__ short f32_to_bf16(float f) {
  union { float f; unsigned u; } v; v.f = f;
  unsigned r = (v.u + 0x7FFFu + ((v.u >> 16) & 1u)) >> 16;  // RNE
  return (short)r;
}

// Async 16B global -> LDS. LDS dest must be wave-uniform base + lane*16
// (m104/m108). Global source address IS per-lane -> pre-swizzled source.
static __device__ __forceinline__ void g2l16(const short* g, short* l) {
  __builtin_amdgcn_global_load_lds(
      (const __attribute__((address_space(1))) void*)g,
      (__attribute__((address_space(3))) void*)l, 16, 0, 0);
}

// ---- Kernel 1: prep. Blocks [0,4096): X fp32->bf16. [4096,4608): W transpose.
__global__ __launch_bounds__(256) void k_prep(const float* __restrict__ X,
                                              const float* __restrict__ Wu,
                                              const float* __restrict__ Wl,
                                              short* __restrict__ Xb,
                                              short* __restrict__ WTu,
                                              short* __restrict__ WTl) {
  const int bid = blockIdx.x;
  if (bid < 4096) {
    int i = bid * 256 + threadIdx.x;  // float4 groups over 16384*256 floats
    const float4 v = ((const float4*)X)[i];
    short4 o;
    o.x = f32_to_bf16(v.x); o.y = f32_to_bf16(v.y);
    o.z = f32_to_bf16(v.z); o.w = f32_to_bf16(v.w);
    ((short4*)Xb)[i] = o;
  } else {
    const int id = bid - 4096;           // [0,512)
    const int z = id >> 8, d = id & 255; // matrix, source row of W
    const float* W = z ? Wl : Wu;
    short* WT = z ? WTl : WTu;
    const int e = threadIdx.x;
    WT[e * DD + d] = f32_to_bf16(W[d * DD + e]);  // WT[e][d] = W[d][e]
  }
}

// ---- Kernel 2: fused stage1+stage2. One block per (list b, 64-row p-strip).
// Grid = 256 blocks (16 strips x 16 lists) = exactly 1/CU; 1024 thr = 16 waves.
// bid = pt*16 + b -> XCD = bid%8 = b%8: 2 lists pinned per XCD L2 (R6: FETCH
// 13MB proves B-reads are L2-hits).
// R6 bottleneck: VGPR=64 left no headroom -> per-ks serialize (load, wait
// vmcnt(0), 16 MFMA) -> MfmaUtil 9.6%, latency-bound. R7: explicit 2-deep
// B-load pipeline (bfA/bfB named buffers, ks0/ks1 issued pre-barrier).
__global__ __launch_bounds__(1024, 4) void k_fused(const short* __restrict__ Xb,
                                                   const short* __restrict__ WTu,
                                                   const short* __restrict__ WTl,
                                                   const float* __restrict__ bu_p,
                                                   const float* __restrict__ bl_p,
                                                   float* __restrict__ out) {
  __shared__ short Asw[64 * 256];  // swizzled Xp strip, 32 KB
  __shared__ short Yu[64 * 256];   // swizzled Y_upper,  32 KB
  __shared__ short Yl[64 * 256];   // swizzled Y_lower,  32 KB

  const int bid = blockIdx.x;
  const int b = bid & 15, pt = bid >> 4;  // pt in [0,16): 64-row strip
  const int t = threadIdx.x, lane = t & 63, w = t >> 6;  // w in [0,16)
  const int r = lane & 15, quad = lane >> 4;
  const size_t listoff = (size_t)b * NL * DD;
  const short* Ap = Xb + listoff + (size_t)pt * 64 * DD;  // 64 x 256 bf16

  // ---- stage Xp into LDS, XOR-swizzled via pre-swizzled global source ----
#pragma unroll
  for (int i = 0; i < 2; ++i) {
    const int c = i * 1024 + t;  // per wave: uniform base + lane*16
    const int src = c ^ ((c >> 5) & 7);
    g2l16(Ap + src * 8, Asw + c * 8);
  }
  __syncthreads();

  // ---- phase 1: Y = Xp * W for both matrices; wave w -> cols [w*16,+16) ----
  {
    const int n0 = w * 16;
    f32x4 aU[4] = {}, aL[4] = {};
#pragma unroll
    for (int ks = 0; ks < 8; ++ks) {
      bf16x8 af[4];
#pragma unroll
      for (int mt = 0; mt < 4; ++mt) {
        const int row = mt * 16 + r;
        const int abyte = (row * 512 + ks * 64 + quad * 16) ^ ((row & 7) << 4);
        af[mt] = *(const bf16x8*)((const char*)Asw + abyte);
      }
      const int off = (n0 + r) * DD + ks * 32 + quad * 8;
      const bf16x8 bfu = *(const bf16x8*)(WTu + off);
      const bf16x8 bfl = *(const bf16x8*)(WTl + off);
#pragma unroll
      for (int mt = 0; mt < 4; ++mt) {
        aU[mt] = __builtin_amdgcn_mfma_f32_16x16x32_bf16(af[mt], bfu, aU[mt], 0, 0, 0);
        aL[mt] = __builtin_amdgcn_mfma_f32_16x16x32_bf16(af[mt], bfl, aL[mt], 0, 0, 0);
      }
    }
    // write Y (bf16) into swizzled LDS: D[m][n]: row = mt*16+quad*4+i, col = n0+r
#pragma unroll
    for (int mt = 0; mt < 4; ++mt)
#pragma unroll
      for (int i = 0; i < 4; ++i) {
        const int row = mt * 16 + quad * 4 + i;
        const int col = n0 + r;
        const int byte = (row * 512 + col * 2) ^ ((row & 7) << 4);
        *(short*)((char*)Yu + byte) = f32_to_bf16(aU[mt][i]);
        *(short*)((char*)Yl + byte) = f32_to_bf16(aL[mt][i]);
      }
  }

  // ---- phase 2 setup; B loads for ks=0,1 issued BEFORE the barrier ----
  const float ub = bu_p[0], lb = bl_p[0];
  float* Ob = out + (size_t)b * NL * NL;
  const int p0 = pt * 64;
  const int qt = w, q0 = qt * 64;
  const short* Bg = Xb + listoff + (size_t)qt * 64 * DD;
  const float bias = (qt >= pt) ? ub : lb;

  auto loadB = [&](bf16x8 (&dst)[4], int ks) {
#pragma unroll
    for (int nt = 0; nt < 4; ++nt)
      dst[nt] = *(const bf16x8*)(Bg + (size_t)(nt * 16 + r) * DD + ks * 32 + quad * 8);
  };
  auto mmaStep = [&](const short* Y, const bf16x8 (&bf)[4], f32x4 (&ac)[4][4], int ks) {
#pragma unroll
    for (int mt = 0; mt < 4; ++mt) {
      const int row = mt * 16 + r;
      const int abyte = (row * 512 + ks * 64 + quad * 16) ^ ((row & 7) << 4);
      const bf16x8 af = *(const bf16x8*)((const char*)Y + abyte);
#pragma unroll
      for (int nt = 0; nt < 4; ++nt)
        ac[nt][mt] = __builtin_amdgcn_mfma_f32_16x16x32_bf16(bf[nt], af, ac[nt][mt], 0, 0, 0);
    }
  };

  bf16x8 bfA[4], bfB[4];
  loadB(bfA, 0);   // in flight across the barrier (overlaps drain)
  loadB(bfB, 1);
  __syncthreads();

  // ---- phase 2: barrier-free; wave w owns q-tile w; 2-deep load pipeline ----
  const short* YA = (qt >= pt) ? Yu : Yl;  // diag tile -> Upper in this pass
  f32x4 acc[4][4] = {};  // [nt][mt]: D rows <- q (B rows), cols <- p (Y rows)
  mmaStep(YA, bfA, acc, 0);  loadB(bfA, 2);
  mmaStep(YA, bfB, acc, 1);  loadB(bfB, 3);
  mmaStep(YA, bfA, acc, 2);  loadB(bfA, 4);
  mmaStep(YA, bfB, acc, 3);  loadB(bfB, 5);
  mmaStep(YA, bfA, acc, 4);  loadB(bfA, 6);
  mmaStep(YA, bfB, acc, 5);  loadB(bfB, 7);
  mmaStep(YA, bfA, acc, 6);
  mmaStep(YA, bfB, acc, 7);

  // stores: lane holds row p0+mt*16+r, 4 consecutive q per f32x4 (L2 merges)
#pragma unroll
  for (int mt = 0; mt < 4; ++mt) {
    float* row = Ob + (size_t)(p0 + mt * 16 + r) * NL;
#pragma unroll
    for (int nt = 0; nt < 4; ++nt) {
      f32x4 v;
#pragma unroll
      for (int i = 0; i < 4; ++i) v[i] = acc[nt][mt][i] + bias;
      *(f32x4*)(row + q0 + nt * 16 + quad * 4) = v;
    }
  }

  // ---- diag fixup: wave pt recomputes lower part with Y_L, overwrites q<p ----
  if (qt == pt) {
    f32x4 accL[4][4] = {};
    loadB(bfA, 0);   // B tile is L2-hot (just read twice)
    loadB(bfB, 1);
    mmaStep(Yl, bfA, accL, 0);  loadB(bfA, 2);
    mmaStep(Yl, bfB, accL, 1);  loadB(bfB, 3);
    mmaStep(Yl, bfA, accL, 2);  loadB(bfA, 4);
    mmaStep(Yl, bfB, accL, 3);  loadB(bfB, 5);
    mmaStep(Yl, bfA, accL, 4);  loadB(bfA, 6);
    mmaStep(Yl, bfB, accL, 5);  loadB(bfB, 7);
    mmaStep(Yl, bfA, accL, 6);
    mmaStep(Yl, bfB, accL, 7);
#pragma unroll
    for (int mt = 0; mt < 4; ++mt) {
      const int p = p0 + mt * 16 + r;
      float* row = Ob + (size_t)p * NL;
#pragma unroll
      for (int nt = 0; nt < 4; ++nt)
#pragma unroll
        for (int i = 0; i < 4; ++i) {
          const int q = q0 + nt * 16 + quad * 4 + i;
          if (q < p) row[q] = accL[nt][mt][i] + lb;
        }
    }
  }
}

extern "C" void kernel_launch(void* const* d_in, const int* in_sizes, int n_in,
                              void* d_out, int out_size, void* d_ws, size_t ws_size,
                              hipStream_t stream) {
  const float* feats = (const float*)d_in[0];   // [B*N, D] fp32
  const float* Wu    = (const float*)d_in[1];   // [1, D, D]
  const float* bu    = (const float*)d_in[2];   // [1]
  const float* Wl    = (const float*)d_in[3];   // [1, D, D]
  const float* bl    = (const float*)d_in[4];   // [1]
  float* out = (float*)d_out;                   // [B, N, N] fp32

  char* ws = (char*)d_ws;
  short* Xb  = (short*)(ws);                                   // 8 MB bf16 X
  short* WTu = (short*)(ws + (size_t)8 * 1024 * 1024);         // 128 KB
  short* WTl = (short*)(ws + (size_t)8 * 1024 * 1024 + DD * DD * 2);

  // Prep: X->bf16 (4096 blocks) + W transpose (512 blocks), one dispatch.
  k_prep<<<4096 + 512, 256, 0, stream>>>(feats, Wu, Wl, Xb, WTu, WTl);

  // Fused stage1+stage2: 256 blocks (16 p-strips x 16 lists), 1024 threads.
  // bid = pt*16 + b  ->  XCD = bid%8 = b%8: each list L2-pinned to one XCD.
  k_fused<<<256, 1024, 0, stream>>>(Xb, WTu, WTl, bu, bl, out);
}